// Round 1
// baseline (276.368 us; speedup 1.0000x reference)
//
#include <hip/hip_runtime.h>
#include <hip/hip_bf16.h>

#define NN     200000
#define FEATD  64
#define BN     4096
#define DEG    32
#define PP     2048
#define EMB    64
#define EPSV   1e-8f

// ws layout (float offsets)
#define WS_SC    0          // float4[NN]  {s0,s1,s2,norm}
#define WS_MISC  800000     // [0..2]=mean_pos  [4..6]=inv_pe  [8..10]=loss accum
#define WS_RF    800016     // [3][BN][EMB]

// ---------------------------------------------------------------- kernel A
// Per node n: sim = relu(feat_n @ rsimTrans); store {dot(pe_r,sim)}_r, ||sim||.
__global__ __launch_bounds__(256) void node_precompute(
    const float* __restrict__ features, const float* __restrict__ rsim,
    const float* __restrict__ pos_embs, float4* __restrict__ node_sc)
{
    __shared__ float rs[64 * 64];   // natural layout rs[f*64+j]
    __shared__ float pe[192];
    int t = threadIdx.x;
    for (int idx = t; idx < 4096; idx += 256) rs[idx] = rsim[idx];
    if (t < 192) pe[t] = pos_embs[t];
    __syncthreads();

    int n = blockIdx.x * 256 + t;
    if (n >= NN) return;

    float fv[64];
    const float4* fp = (const float4*)(features + (size_t)n * FEATD);
#pragma unroll
    for (int i = 0; i < 16; ++i) {
        float4 v = fp[i];
        fv[4*i] = v.x; fv[4*i+1] = v.y; fv[4*i+2] = v.z; fv[4*i+3] = v.w;
    }

    const float4* rs4 = (const float4*)rs;
    const float4* pe4 = (const float4*)pe;
    float s0 = 0.f, s1 = 0.f, s2 = 0.f, q = 0.f;
    for (int jb = 0; jb < 16; ++jb) {            // 4 sim components per iter
        float4 sim = make_float4(0.f, 0.f, 0.f, 0.f);
#pragma unroll
        for (int f = 0; f < 64; ++f) {           // fully unrolled: fv[] stays in regs
            float4 rr = rs4[f * 16 + jb];
            sim.x += fv[f] * rr.x; sim.y += fv[f] * rr.y;
            sim.z += fv[f] * rr.z; sim.w += fv[f] * rr.w;
        }
        sim.x = fmaxf(sim.x, 0.f); sim.y = fmaxf(sim.y, 0.f);
        sim.z = fmaxf(sim.z, 0.f); sim.w = fmaxf(sim.w, 0.f);
        float4 p0 = pe4[jb], p1 = pe4[16 + jb], p2 = pe4[32 + jb];
        s0 += sim.x*p0.x + sim.y*p0.y + sim.z*p0.z + sim.w*p0.w;
        s1 += sim.x*p1.x + sim.y*p1.y + sim.z*p1.z + sim.w*p1.w;
        s2 += sim.x*p2.x + sim.y*p2.y + sim.z*p2.z + sim.w*p2.w;
        q  += sim.x*sim.x + sim.y*sim.y + sim.z*sim.z + sim.w*sim.w;
    }
    node_sc[n] = make_float4(s0, s1, s2, sqrtf(q));
}

// ---------------------------------------------------------------- kernel B
// pe norms, mean(pos_scores) per relation, zero loss accumulators.
__global__ __launch_bounds__(256) void pos_stats(
    const int* __restrict__ pos_nodes, const float4* __restrict__ node_sc,
    const float* __restrict__ pos_embs, float* __restrict__ misc)
{
    __shared__ float pe[192];
    __shared__ float invpe[3];
    __shared__ float wsum[4][3];
    int t = threadIdx.x;
    if (t < 192) pe[t] = pos_embs[t];
    __syncthreads();
    if (t < 3) {
        float q = 0.f;
        for (int j = 0; j < 64; ++j) { float v = pe[t*64 + j]; q += v * v; }
        float inv = 1.f / fmaxf(sqrtf(q), EPSV);
        invpe[t] = inv;
        misc[4 + t] = inv;
        misc[8 + t] = 0.f;          // zero loss accum (fresh every launch)
    }
    __syncthreads();
    float s[3] = {0.f, 0.f, 0.f};
    for (int p = t; p < PP; p += 256) {
        int n = pos_nodes[p];
        float4 sc = node_sc[n];
        float invn = 1.f / fmaxf(sc.w, EPSV);
        s[0] += sc.x * invpe[0] * invn;
        s[1] += sc.y * invpe[1] * invn;
        s[2] += sc.z * invpe[2] * invn;
    }
    int wv = t >> 6;
#pragma unroll
    for (int r = 0; r < 3; ++r)
        for (int off = 32; off; off >>= 1) s[r] += __shfl_down(s[r], off);
    if ((t & 63) == 0) { wsum[wv][0] = s[0]; wsum[wv][1] = s[1]; wsum[wv][2] = s[2]; }
    __syncthreads();
    if (t < 3)
        misc[t] = (wsum[0][t] + wsum[1][t] + wsum[2][t] + wsum[3][t]) / (float)PP;
}

// ---------------------------------------------------------------- kernel C
// One wave per (b, r): score 32 neighbors, stable top-k set, aggregate
// features of selected, rfeat = relu(agg @ W_r), loss partial.
__global__ __launch_bounds__(256) void relation_agg(
    const int* __restrict__ n1, const int* __restrict__ n2, const int* __restrict__ n3,
    const float* __restrict__ features, const float4* __restrict__ node_sc,
    const float* __restrict__ W1, const float* __restrict__ W2, const float* __restrict__ W3,
    const float* __restrict__ misc, float* __restrict__ lossacc,
    float* __restrict__ rfeat, const int* __restrict__ smp)
{
    int r = blockIdx.y;
    const int*   neigh = (r == 0) ? n1 : (r == 1) ? n2 : n3;
    const float* W     = (r == 0) ? W1 : (r == 1) ? W2 : W3;
    int k = smp[0];
    int t = threadIdx.x;
    int wv = t >> 6, lane = t & 63;
    int b = blockIdx.x * 4 + wv;
    float inv_pe  = misc[4 + r];
    float mean_pos = misc[r];

    __shared__ int sel_ids[4][32];

    float s = -1e30f;
    int   n = 0;
    if (lane < 32) {
        n = neigh[b * DEG + lane];
        float4 sc = node_sc[n];
        float num = (r == 0) ? sc.x : (r == 1) ? sc.y : sc.z;
        s = num * inv_pe / fmaxf(sc.w, EPSV);
    }
    // stable rank among 32 scores (ties -> lower index first), matches lax.top_k
    int cnt = 0;
#pragma unroll
    for (int d2 = 0; d2 < 32; ++d2) {
        float v = __shfl(s, d2);
        cnt += ((v > s) || (v == s && d2 < lane)) ? 1 : 0;
    }
    bool sel = (lane < 32) && (cnt < k);
    if (sel) sel_ids[wv][cnt] = n;       // rank is a unique slot in [0,k)

    float lv = sel ? (s - mean_pos) * (s - mean_pos) : 0.f;
    for (int off = 32; off; off >>= 1) lv += __shfl_down(lv, off);
    if (lane == 0) atomicAdd(&lossacc[r], lv);

    __syncthreads();

    float sum = 0.f;
    for (int kk = 0; kk < k; ++kk) {
        int nid = sel_ids[wv][kk];
        sum += features[(size_t)nid * FEATD + lane];   // coalesced 256B row
    }
    float agg = sum / (float)k;

    // rfeat[e] = relu(sum_j agg[j] * W[j][e]),  e = lane
    float acc = 0.f;
#pragma unroll
    for (int j = 0; j < 64; ++j) {
        float aj = __shfl(agg, j);
        acc += aj * W[j * EMB + lane];   // L1-hot, coalesced
    }
    rfeat[((size_t)r * BN + b) * EMB + lane] = fmaxf(acc, 0.f);
}

// ---------------------------------------------------------------- kernel D
// combined[e][b] = relu(cat[b] . weight[:,e]); cat staged transposed in LDS.
__global__ __launch_bounds__(256) void final_mm(
    const int* __restrict__ nodes, const float* __restrict__ features,
    const float* __restrict__ rfeat, const float* __restrict__ weight,
    const float* __restrict__ lossacc, const int* __restrict__ smp,
    float* __restrict__ out)
{
    __shared__ float catT[256][65];      // catT[i][b], pad 65 -> conflict-free
    int t = threadIdx.x;
    int b0 = blockIdx.x * 64;

    for (int idx = t; idx < 64 * 64; idx += 256) {
        int bb = idx >> 6, f = idx & 63;
        catT[f][bb] = features[(size_t)nodes[b0 + bb] * FEATD + f];
    }
#pragma unroll
    for (int r = 0; r < 3; ++r)
        for (int idx = t; idx < 64 * 64; idx += 256) {
            int bb = idx >> 6, j = idx & 63;
            catT[64 + r * 64 + j][bb] = rfeat[((size_t)r * BN + b0 + bb) * EMB + j];
        }
    __syncthreads();

    int wv   = __builtin_amdgcn_readfirstlane(t >> 6);  // force wave-uniform
    int lane = t & 63;
    int e0   = wv * 16;

    float acc[16];
#pragma unroll
    for (int e = 0; e < 16; ++e) acc[e] = 0.f;

    for (int i0 = 0; i0 < 256; i0 += 32) {
        float c[32];
#pragma unroll
        for (int ii = 0; ii < 32; ++ii) c[ii] = catT[i0 + ii][lane];
#pragma unroll
        for (int e = 0; e < 16; ++e) {
            float a = acc[e];
#pragma unroll
            for (int ii = 0; ii < 32; ++ii)
                a += c[ii] * weight[(i0 + ii) * EMB + e0 + e];  // scalar loads
            acc[e] = a;
        }
    }
#pragma unroll
    for (int e = 0; e < 16; ++e)
        out[(size_t)(e0 + e) * BN + b0 + lane] = fmaxf(acc[e], 0.f);

    if (blockIdx.x == 0 && t == 0) {
        int k = smp[0];
        out[(size_t)EMB * BN] =
            (lossacc[0] + lossacc[1] + lossacc[2]) / (3.f * (float)BN * (float)k);
    }
}

// ----------------------------------------------------------------
extern "C" void kernel_launch(void* const* d_in, const int* in_sizes, int n_in,
                              void* d_out, int out_size, void* d_ws, size_t ws_size,
                              hipStream_t stream) {
    const int*   nodes     = (const int*)  d_in[0];
    // d_in[1] labels: unused
    const int*   neigh1    = (const int*)  d_in[2];
    const int*   neigh2    = (const int*)  d_in[3];
    const int*   neigh3    = (const int*)  d_in[4];
    const int*   pos_nodes = (const int*)  d_in[5];
    const float* features  = (const float*)d_in[6];
    const float* weight    = (const float*)d_in[7];
    const float* rsim      = (const float*)d_in[8];
    const float* pos_embs  = (const float*)d_in[9];
    const float* W1        = (const float*)d_in[10];
    const float* W2        = (const float*)d_in[11];
    const float* W3        = (const float*)d_in[12];
    const int*   smp       = (const int*)  d_in[13];
    float* out = (float*)d_out;
    float* ws  = (float*)d_ws;

    float4* node_sc = (float4*)(ws + WS_SC);
    float*  misc    = ws + WS_MISC;
    float*  lossacc = ws + WS_MISC + 8;
    float*  rfeat   = ws + WS_RF;

    node_precompute<<<dim3((NN + 255) / 256), dim3(256), 0, stream>>>(
        features, rsim, pos_embs, node_sc);
    pos_stats<<<dim3(1), dim3(256), 0, stream>>>(pos_nodes, node_sc, pos_embs, misc);
    relation_agg<<<dim3(BN / 4, 3), dim3(256), 0, stream>>>(
        neigh1, neigh2, neigh3, features, node_sc, W1, W2, W3,
        misc, lossacc, rfeat, smp);
    final_mm<<<dim3(BN / 64), dim3(256), 0, stream>>>(
        nodes, features, rfeat, weight, lossacc, smp, out);
}

// Round 2
// 134.900 us; speedup vs baseline: 2.0487x; 2.0487x over previous
//
#include <hip/hip_runtime.h>
#include <hip/hip_bf16.h>

#define NN     200000
#define FEATD  64
#define BN     4096
#define DEG    32
#define PP     2048
#define EMB    64
#define EPSV   1e-8f

// ws layout (float offsets)
#define WS_SC    0          // float4[NN]  {s0,s1,s2,norm}
#define WS_MISC  800000     // [0..2]=mean_pos  [4..6]=inv_pe
#define WS_LOSS  800064     // 24 slots, stride 32 floats (128B apart)
#define WS_RF    800832     // [3][BN][EMB]

// ---------------------------------------------------------------- kernel A
// Per node n: sim = relu(feat_n @ rsimTrans); store {dot(pe_r,sim)}_r, ||sim||.
__global__ __launch_bounds__(256) void node_precompute(
    const float* __restrict__ features, const float* __restrict__ rsim,
    const float* __restrict__ pos_embs, float4* __restrict__ node_sc)
{
    __shared__ float rs[64 * 64];   // natural layout rs[f*64+j]
    __shared__ float pe[192];
    int t = threadIdx.x;
    for (int idx = t; idx < 4096; idx += 256) rs[idx] = rsim[idx];
    if (t < 192) pe[t] = pos_embs[t];
    __syncthreads();

    int n = blockIdx.x * 256 + t;
    if (n >= NN) return;

    float fv[64];
    const float4* fp = (const float4*)(features + (size_t)n * FEATD);
#pragma unroll
    for (int i = 0; i < 16; ++i) {
        float4 v = fp[i];
        fv[4*i] = v.x; fv[4*i+1] = v.y; fv[4*i+2] = v.z; fv[4*i+3] = v.w;
    }

    const float4* rs4 = (const float4*)rs;
    const float4* pe4 = (const float4*)pe;
    float s0 = 0.f, s1 = 0.f, s2 = 0.f, q = 0.f;
    for (int jb = 0; jb < 16; ++jb) {            // 4 sim components per iter
        float4 sim = make_float4(0.f, 0.f, 0.f, 0.f);
#pragma unroll
        for (int f = 0; f < 64; ++f) {           // fully unrolled: fv[] stays in regs
            float4 rr = rs4[f * 16 + jb];
            sim.x += fv[f] * rr.x; sim.y += fv[f] * rr.y;
            sim.z += fv[f] * rr.z; sim.w += fv[f] * rr.w;
        }
        sim.x = fmaxf(sim.x, 0.f); sim.y = fmaxf(sim.y, 0.f);
        sim.z = fmaxf(sim.z, 0.f); sim.w = fmaxf(sim.w, 0.f);
        float4 p0 = pe4[jb], p1 = pe4[16 + jb], p2 = pe4[32 + jb];
        s0 += sim.x*p0.x + sim.y*p0.y + sim.z*p0.z + sim.w*p0.w;
        s1 += sim.x*p1.x + sim.y*p1.y + sim.z*p1.z + sim.w*p1.w;
        s2 += sim.x*p2.x + sim.y*p2.y + sim.z*p2.z + sim.w*p2.w;
        q  += sim.x*sim.x + sim.y*sim.y + sim.z*sim.z + sim.w*sim.w;
    }
    node_sc[n] = make_float4(s0, s1, s2, sqrtf(q));
}

// ---------------------------------------------------------------- kernel B
// pe inverse norms, mean(pos_scores) per relation, zero loss slots.
__global__ __launch_bounds__(1024) void pos_stats(
    const int* __restrict__ pos_nodes, const float4* __restrict__ node_sc,
    const float* __restrict__ pos_embs, float* __restrict__ misc,
    float* __restrict__ lossacc)
{
    __shared__ float invpe_s[3];
    __shared__ float wsum[16][3];
    int t = threadIdx.x, wv = t >> 6, lane = t & 63;

    if (t < 24) lossacc[t * 32] = 0.f;           // zero spread loss slots

    // pe norms: waves 0..2 each own one pos_emb row (t in [r*64, r*64+64))
    float pv = (t < 192) ? pos_embs[t] : 0.f;
    float q = pv * pv;
#pragma unroll
    for (int off = 32; off; off >>= 1) q += __shfl_down(q, off);
    if (t < 192 && lane == 0) {
        float inv = 1.f / fmaxf(sqrtf(q), EPSV);
        invpe_s[wv] = inv;
        misc[4 + wv] = inv;
    }
    __syncthreads();

    float i0 = invpe_s[0], i1 = invpe_s[1], i2 = invpe_s[2];
    float s0 = 0.f, s1 = 0.f, s2 = 0.f;
    for (int p = t; p < PP; p += 1024) {
        int n = pos_nodes[p];
        float4 sc = node_sc[n];
        float invn = 1.f / fmaxf(sc.w, EPSV);
        s0 += sc.x * i0 * invn;
        s1 += sc.y * i1 * invn;
        s2 += sc.z * i2 * invn;
    }
#pragma unroll
    for (int off = 32; off; off >>= 1) {
        s0 += __shfl_down(s0, off);
        s1 += __shfl_down(s1, off);
        s2 += __shfl_down(s2, off);
    }
    if (lane == 0) { wsum[wv][0] = s0; wsum[wv][1] = s1; wsum[wv][2] = s2; }
    __syncthreads();
    if (t < 3) {
        float s = 0.f;
        for (int w = 0; w < 16; ++w) s += wsum[w][t];
        misc[t] = s / (float)PP;
    }
}

// ---------------------------------------------------------------- kernel C
// One wave per (b, r): score 32 neighbors, stable top-k, parallel 16-row
// feature aggregate (4 independent dwordx4 loads), rfeat = relu(agg @ W_r).
__global__ __launch_bounds__(256) void relation_agg(
    const int* __restrict__ n1, const int* __restrict__ n2, const int* __restrict__ n3,
    const float* __restrict__ features, const float4* __restrict__ node_sc,
    const float* __restrict__ W1, const float* __restrict__ W2, const float* __restrict__ W3,
    const float* __restrict__ misc, float* __restrict__ lossacc,
    float* __restrict__ rfeat, const int* __restrict__ smp)
{
    int r = blockIdx.y;
    const int*   neigh = (r == 0) ? n1 : (r == 1) ? n2 : n3;
    const float* W     = (r == 0) ? W1 : (r == 1) ? W2 : W3;
    int k = smp[0];
    int t = threadIdx.x;
    int wv = t >> 6, lane = t & 63;
    int b = blockIdx.x * 4 + wv;
    float inv_pe   = misc[4 + r];
    float mean_pos = misc[r];

    __shared__ int sel_ids[4][32];

    // ---- score phase (lanes 0-31)
    float s = -1e30f;
    int   n = 0;
    if (lane < 32) {
        n = neigh[b * DEG + lane];
        float4 sc = node_sc[n];
        float num = (r == 0) ? sc.x : (r == 1) ? sc.y : sc.z;
        s = num * inv_pe / fmaxf(sc.w, EPSV);
    }
    // stable rank among 32 scores (ties -> lower index), matches lax.top_k
    int cnt = 0;
#pragma unroll
    for (int d2 = 0; d2 < 32; ++d2) {
        float v = __shfl(s, d2);
        cnt += ((v > s) || (v == s && d2 < lane)) ? 1 : 0;
    }
    bool sel = (lane < 32) && (cnt < k);
    if (sel) sel_ids[wv][cnt] = n;       // rank = unique slot in [0,k)

    float lv = sel ? (s - mean_pos) * (s - mean_pos) : 0.f;
#pragma unroll
    for (int off = 32; off; off >>= 1) lv += __shfl_down(lv, off);
    if (lane == 0)
        atomicAdd(&lossacc[(r * 8 + (blockIdx.x & 7)) * 32], lv);
    // no __syncthreads: sel_ids producer/consumer are the same wave (lgkmcnt)

    // ---- aggregate phase: 16 lanes per row, 4 rows per load wavefront
    const float4* F = (const float4*)features;
    int col   = lane & 15;           // float4 index within a 64-float row
    int rbase = lane >> 4;           // 0..3
    float4 a = make_float4(0.f, 0.f, 0.f, 0.f);
    if (k == 16) {
        int nid0 = sel_ids[wv][rbase];
        int nid1 = sel_ids[wv][rbase + 4];
        int nid2 = sel_ids[wv][rbase + 8];
        int nid3 = sel_ids[wv][rbase + 12];
        float4 v0 = F[(size_t)nid0 * 16 + col];
        float4 v1 = F[(size_t)nid1 * 16 + col];
        float4 v2 = F[(size_t)nid2 * 16 + col];
        float4 v3 = F[(size_t)nid3 * 16 + col];
        a.x = v0.x + v1.x + v2.x + v3.x;
        a.y = v0.y + v1.y + v2.y + v3.y;
        a.z = v0.z + v1.z + v2.z + v3.z;
        a.w = v0.w + v1.w + v2.w + v3.w;
    } else {
        for (int row0 = 0; row0 < k; row0 += 4) {
            int row = row0 + rbase;
            if (row < k) {
                int nid = sel_ids[wv][row];
                float4 v = F[(size_t)nid * 16 + col];
                a.x += v.x; a.y += v.y; a.z += v.z; a.w += v.w;
            }
        }
    }
    // allreduce across the 4 row-groups (xor 16, 32)
#pragma unroll
    for (int off = 16; off <= 32; off <<= 1) {
        a.x += __shfl_xor(a.x, off);
        a.y += __shfl_xor(a.y, off);
        a.z += __shfl_xor(a.z, off);
        a.w += __shfl_xor(a.w, off);
    }
    float inv_k = 1.f / (float)k;
    a.x *= inv_k; a.y *= inv_k; a.z *= inv_k; a.w *= inv_k;
    // lane l holds agg[cols (l&15)*4 .. +4], replicated across l>>4

    // ---- rfeat[e=lane] = relu(sum_j agg[j] * W[j][e])
    float acc = 0.f;
#pragma unroll
    for (int j4 = 0; j4 < 16; ++j4) {
        float a0 = __shfl(a.x, j4);
        float a1 = __shfl(a.y, j4);
        float a2 = __shfl(a.z, j4);
        float a3 = __shfl(a.w, j4);
        acc += a0 * W[(j4 * 4 + 0) * EMB + lane]
             + a1 * W[(j4 * 4 + 1) * EMB + lane]
             + a2 * W[(j4 * 4 + 2) * EMB + lane]
             + a3 * W[(j4 * 4 + 3) * EMB + lane];
    }
    rfeat[((size_t)r * BN + b) * EMB + lane] = fmaxf(acc, 0.f);
}

// ---------------------------------------------------------------- kernel D
// combined[e][b] = relu(cat[b] . weight[:,e]); cat staged transposed in LDS.
__global__ __launch_bounds__(256) void final_mm(
    const int* __restrict__ nodes, const float* __restrict__ features,
    const float* __restrict__ rfeat, const float* __restrict__ weight,
    const float* __restrict__ lossacc, const int* __restrict__ smp,
    float* __restrict__ out)
{
    __shared__ float catT[256][65];      // catT[i][b], pad 65 -> conflict-free
    __shared__ float ls[24];
    int t = threadIdx.x;
    int b0 = blockIdx.x * 64;

    if (blockIdx.x == 0 && t < 24) ls[t] = lossacc[t * 32];

    for (int idx = t; idx < 64 * 64; idx += 256) {
        int bb = idx >> 6, f = idx & 63;
        catT[f][bb] = features[(size_t)nodes[b0 + bb] * FEATD + f];
    }
#pragma unroll
    for (int r = 0; r < 3; ++r)
        for (int idx = t; idx < 64 * 64; idx += 256) {
            int bb = idx >> 6, j = idx & 63;
            catT[64 + r * 64 + j][bb] = rfeat[((size_t)r * BN + b0 + bb) * EMB + j];
        }
    __syncthreads();

    int wv   = __builtin_amdgcn_readfirstlane(t >> 6);  // force wave-uniform
    int lane = t & 63;
    int e0   = wv * 16;

    float acc[16];
#pragma unroll
    for (int e = 0; e < 16; ++e) acc[e] = 0.f;

    for (int i0 = 0; i0 < 256; i0 += 32) {
        float c[32];
#pragma unroll
        for (int ii = 0; ii < 32; ++ii) c[ii] = catT[i0 + ii][lane];
#pragma unroll
        for (int e = 0; e < 16; ++e) {
            float aa = acc[e];
#pragma unroll
            for (int ii = 0; ii < 32; ++ii)
                aa += c[ii] * weight[(i0 + ii) * EMB + e0 + e];  // scalar loads
            acc[e] = aa;
        }
    }
#pragma unroll
    for (int e = 0; e < 16; ++e)
        out[(size_t)(e0 + e) * BN + b0 + lane] = fmaxf(acc[e], 0.f);

    if (blockIdx.x == 0 && t == 0) {
        int k = smp[0];
        float s = 0.f;
        for (int i = 0; i < 24; ++i) s += ls[i];
        out[(size_t)EMB * BN] = s / (3.f * (float)BN * (float)k);
    }
}

// ----------------------------------------------------------------
extern "C" void kernel_launch(void* const* d_in, const int* in_sizes, int n_in,
                              void* d_out, int out_size, void* d_ws, size_t ws_size,
                              hipStream_t stream) {
    const int*   nodes     = (const int*)  d_in[0];
    // d_in[1] labels: unused
    const int*   neigh1    = (const int*)  d_in[2];
    const int*   neigh2    = (const int*)  d_in[3];
    const int*   neigh3    = (const int*)  d_in[4];
    const int*   pos_nodes = (const int*)  d_in[5];
    const float* features  = (const float*)d_in[6];
    const float* weight    = (const float*)d_in[7];
    const float* rsim      = (const float*)d_in[8];
    const float* pos_embs  = (const float*)d_in[9];
    const float* W1        = (const float*)d_in[10];
    const float* W2        = (const float*)d_in[11];
    const float* W3        = (const float*)d_in[12];
    const int*   smp       = (const int*)  d_in[13];
    float* out = (float*)d_out;
    float* ws  = (float*)d_ws;

    float4* node_sc = (float4*)(ws + WS_SC);
    float*  misc    = ws + WS_MISC;
    float*  lossacc = ws + WS_LOSS;
    float*  rfeat   = ws + WS_RF;

    node_precompute<<<dim3((NN + 255) / 256), dim3(256), 0, stream>>>(
        features, rsim, pos_embs, node_sc);
    pos_stats<<<dim3(1), dim3(1024), 0, stream>>>(pos_nodes, node_sc, misc ? pos_embs : pos_embs, misc, lossacc);
    relation_agg<<<dim3(BN / 4, 3), dim3(256), 0, stream>>>(
        neigh1, neigh2, neigh3, features, node_sc, W1, W2, W3,
        misc, lossacc, rfeat, smp);
    final_mm<<<dim3(BN / 64), dim3(256), 0, stream>>>(
        nodes, features, rfeat, weight, lossacc, smp, out);
}

// Round 3
// 96.396 us; speedup vs baseline: 2.8670x; 1.3994x over previous
//
#include <hip/hip_runtime.h>
#include <hip/hip_bf16.h>

#define NN     200000
#define FEATD  64
#define BN     4096
#define DEG    32
#define PP     2048
#define EMB    64
#define EPSV   1e-8f

// ws layout (float offsets)
#define WS_SC    0          // float4[NN]  {s0,s1,s2,norm}
#define WS_MISC  800000     // [0..2]=mean_pos  [4..6]=inv_pe
#define WS_LOSS  800064     // 24 slots, stride 32 floats (128B apart)
#define WS_RF    800832     // [3][BN][EMB]

// ---------------------------------------------------------------- kernel A
// Per node n: sim = relu(feat_n @ rsimTrans); store {dot(pe_r,sim)}_r, ||sim||.
__global__ __launch_bounds__(256) void node_precompute(
    const float* __restrict__ features, const float* __restrict__ rsim,
    const float* __restrict__ pos_embs, float4* __restrict__ node_sc)
{
    __shared__ float rs[64 * 64];   // natural layout rs[f*64+j]
    __shared__ float pe[192];
    int t = threadIdx.x;
    for (int idx = t; idx < 4096; idx += 256) rs[idx] = rsim[idx];
    if (t < 192) pe[t] = pos_embs[t];
    __syncthreads();

    int n = blockIdx.x * 256 + t;
    if (n >= NN) return;

    float fv[64];
    const float4* fp = (const float4*)(features + (size_t)n * FEATD);
#pragma unroll
    for (int i = 0; i < 16; ++i) {
        float4 v = fp[i];
        fv[4*i] = v.x; fv[4*i+1] = v.y; fv[4*i+2] = v.z; fv[4*i+3] = v.w;
    }

    const float4* rs4 = (const float4*)rs;
    const float4* pe4 = (const float4*)pe;
    float s0 = 0.f, s1 = 0.f, s2 = 0.f, q = 0.f;
    for (int jb = 0; jb < 16; ++jb) {            // 4 sim components per iter
        float4 sim = make_float4(0.f, 0.f, 0.f, 0.f);
#pragma unroll
        for (int f = 0; f < 64; ++f) {           // fully unrolled: fv[] stays in regs
            float4 rr = rs4[f * 16 + jb];
            sim.x += fv[f] * rr.x; sim.y += fv[f] * rr.y;
            sim.z += fv[f] * rr.z; sim.w += fv[f] * rr.w;
        }
        sim.x = fmaxf(sim.x, 0.f); sim.y = fmaxf(sim.y, 0.f);
        sim.z = fmaxf(sim.z, 0.f); sim.w = fmaxf(sim.w, 0.f);
        float4 p0 = pe4[jb], p1 = pe4[16 + jb], p2 = pe4[32 + jb];
        s0 += sim.x*p0.x + sim.y*p0.y + sim.z*p0.z + sim.w*p0.w;
        s1 += sim.x*p1.x + sim.y*p1.y + sim.z*p1.z + sim.w*p1.w;
        s2 += sim.x*p2.x + sim.y*p2.y + sim.z*p2.z + sim.w*p2.w;
        q  += sim.x*sim.x + sim.y*sim.y + sim.z*sim.z + sim.w*sim.w;
    }
    node_sc[n] = make_float4(s0, s1, s2, sqrtf(q));
}

// ---------------------------------------------------------------- kernel B
// pe inverse norms, mean(pos_scores) per relation, zero loss slots.
__global__ __launch_bounds__(1024) void pos_stats(
    const int* __restrict__ pos_nodes, const float4* __restrict__ node_sc,
    const float* __restrict__ pos_embs, float* __restrict__ misc,
    float* __restrict__ lossacc)
{
    __shared__ float invpe_s[3];
    __shared__ float wsum[16][3];
    int t = threadIdx.x, wv = t >> 6, lane = t & 63;

    if (t < 24) lossacc[t * 32] = 0.f;           // zero spread loss slots

    // pe norms: waves 0..2 each own one pos_emb row
    float pv = (t < 192) ? pos_embs[t] : 0.f;
    float q = pv * pv;
#pragma unroll
    for (int off = 32; off; off >>= 1) q += __shfl_down(q, off);
    if (t < 192 && lane == 0) {
        float inv = 1.f / fmaxf(sqrtf(q), EPSV);
        invpe_s[wv] = inv;
        misc[4 + wv] = inv;
    }
    __syncthreads();

    float i0 = invpe_s[0], i1 = invpe_s[1], i2 = invpe_s[2];
    float s0 = 0.f, s1 = 0.f, s2 = 0.f;
    for (int p = t; p < PP; p += 1024) {
        int n = pos_nodes[p];
        float4 sc = node_sc[n];
        float invn = 1.f / fmaxf(sc.w, EPSV);
        s0 += sc.x * i0 * invn;
        s1 += sc.y * i1 * invn;
        s2 += sc.z * i2 * invn;
    }
#pragma unroll
    for (int off = 32; off; off >>= 1) {
        s0 += __shfl_down(s0, off);
        s1 += __shfl_down(s1, off);
        s2 += __shfl_down(s2, off);
    }
    if (lane == 0) { wsum[wv][0] = s0; wsum[wv][1] = s1; wsum[wv][2] = s2; }
    __syncthreads();
    if (t < 3) {
        float s = 0.f;
        for (int w = 0; w < 16; ++w) s += wsum[w][t];
        misc[t] = s / (float)PP;
    }
}

// ---------------------------------------------------------------- kernel C
// One wave per (b, r): score 32 neighbors, stable top-k, parallel 16-row
// feature aggregate (4 independent dwordx4 loads), rfeat = relu(agg @ W_r).
__global__ __launch_bounds__(256) void relation_agg(
    const int* __restrict__ n1, const int* __restrict__ n2, const int* __restrict__ n3,
    const float* __restrict__ features, const float4* __restrict__ node_sc,
    const float* __restrict__ W1, const float* __restrict__ W2, const float* __restrict__ W3,
    const float* __restrict__ misc, float* __restrict__ lossacc,
    float* __restrict__ rfeat, const int* __restrict__ smp)
{
    int r = blockIdx.y;
    const int*   neigh = (r == 0) ? n1 : (r == 1) ? n2 : n3;
    const float* W     = (r == 0) ? W1 : (r == 1) ? W2 : W3;
    int k = smp[0];
    int t = threadIdx.x;
    int wv = t >> 6, lane = t & 63;
    int b = blockIdx.x * 4 + wv;
    float inv_pe   = misc[4 + r];
    float mean_pos = misc[r];

    __shared__ int sel_ids[4][32];

    // ---- score phase (lanes 0-31)
    float s = -1e30f;
    int   n = 0;
    if (lane < 32) {
        n = neigh[b * DEG + lane];
        float4 sc = node_sc[n];
        float num = (r == 0) ? sc.x : (r == 1) ? sc.y : sc.z;
        s = num * inv_pe / fmaxf(sc.w, EPSV);
    }
    // stable rank among 32 scores (ties -> lower index), matches lax.top_k
    int cnt = 0;
#pragma unroll
    for (int d2 = 0; d2 < 32; ++d2) {
        float v = __shfl(s, d2);
        cnt += ((v > s) || (v == s && d2 < lane)) ? 1 : 0;
    }
    bool sel = (lane < 32) && (cnt < k);
    if (sel) sel_ids[wv][cnt] = n;       // rank = unique slot in [0,k)

    float lv = sel ? (s - mean_pos) * (s - mean_pos) : 0.f;
#pragma unroll
    for (int off = 32; off; off >>= 1) lv += __shfl_down(lv, off);
    if (lane == 0)
        atomicAdd(&lossacc[(r * 8 + (blockIdx.x & 7)) * 32], lv);
    // no __syncthreads: sel_ids producer/consumer are the same wave (lgkmcnt)

    // ---- aggregate phase: 16 lanes per row, 4 rows per load wavefront
    const float4* F = (const float4*)features;
    int col   = lane & 15;           // float4 index within a 64-float row
    int rbase = lane >> 4;           // 0..3
    float4 a = make_float4(0.f, 0.f, 0.f, 0.f);
    if (k == 16) {
        int nid0 = sel_ids[wv][rbase];
        int nid1 = sel_ids[wv][rbase + 4];
        int nid2 = sel_ids[wv][rbase + 8];
        int nid3 = sel_ids[wv][rbase + 12];
        float4 v0 = F[(size_t)nid0 * 16 + col];
        float4 v1 = F[(size_t)nid1 * 16 + col];
        float4 v2 = F[(size_t)nid2 * 16 + col];
        float4 v3 = F[(size_t)nid3 * 16 + col];
        a.x = v0.x + v1.x + v2.x + v3.x;
        a.y = v0.y + v1.y + v2.y + v3.y;
        a.z = v0.z + v1.z + v2.z + v3.z;
        a.w = v0.w + v1.w + v2.w + v3.w;
    } else {
        for (int row0 = 0; row0 < k; row0 += 4) {
            int row = row0 + rbase;
            if (row < k) {
                int nid = sel_ids[wv][row];
                float4 v = F[(size_t)nid * 16 + col];
                a.x += v.x; a.y += v.y; a.z += v.z; a.w += v.w;
            }
        }
    }
    // allreduce across the 4 row-groups (xor 16, 32)
#pragma unroll
    for (int off = 16; off <= 32; off <<= 1) {
        a.x += __shfl_xor(a.x, off);
        a.y += __shfl_xor(a.y, off);
        a.z += __shfl_xor(a.z, off);
        a.w += __shfl_xor(a.w, off);
    }
    float inv_k = 1.f / (float)k;
    a.x *= inv_k; a.y *= inv_k; a.z *= inv_k; a.w *= inv_k;
    // lane l holds agg[cols (l&15)*4 .. +4], replicated across l>>4

    // ---- rfeat[e=lane] = relu(sum_j agg[j] * W[j][e])
    float acc = 0.f;
#pragma unroll
    for (int j4 = 0; j4 < 16; ++j4) {
        float a0 = __shfl(a.x, j4);
        float a1 = __shfl(a.y, j4);
        float a2 = __shfl(a.z, j4);
        float a3 = __shfl(a.w, j4);
        acc += a0 * W[(j4 * 4 + 0) * EMB + lane]
             + a1 * W[(j4 * 4 + 1) * EMB + lane]
             + a2 * W[(j4 * 4 + 2) * EMB + lane]
             + a3 * W[(j4 * 4 + 3) * EMB + lane];
    }
    rfeat[((size_t)r * BN + b) * EMB + lane] = fmaxf(acc, 0.f);
}

// ---------------------------------------------------------------- kernel D
// combined[e][b] = relu(cat[b] . weight[:,e]).
// 512 blocks, b-tile = 8. weight staged TRANSPOSED in LDS (stride 260 floats:
// 16B-aligned rows, superbank (65e+i/4)%8 -> conflict-free ds_read_b128).
// lane = e, wave owns 2 b-columns; cat columns broadcast from LDS.
#define WSTRIDE 260
#define CSTRIDE 264
__global__ __launch_bounds__(256) void final_mm(
    const int* __restrict__ nodes, const float* __restrict__ features,
    const float* __restrict__ rfeat, const float* __restrict__ weight,
    const float* __restrict__ lossacc, const int* __restrict__ smp,
    float* __restrict__ out)
{
    __shared__ float wgtT[64 * WSTRIDE];   // wgtT[e][i] = weight[i][e]
    __shared__ float cat_b[8 * CSTRIDE];   // cat_b[bb][i]
    __shared__ float trans[8 * 65];        // output transpose tile
    __shared__ float ls[24];
    int t = threadIdx.x;
    int b0 = blockIdx.x * 8;

    if (blockIdx.x == 0 && t < 24) ls[t] = lossacc[t * 32];

    // stage weight transposed: 4096 float4 / 256 threads = 16 iters
    const float4* wp4 = (const float4*)weight;
    for (int idx = t; idx < 4096; idx += 256) {
        int i = idx >> 4, e0 = (idx & 15) << 2;
        float4 w = wp4[idx];
        wgtT[(e0 + 0) * WSTRIDE + i] = w.x;
        wgtT[(e0 + 1) * WSTRIDE + i] = w.y;
        wgtT[(e0 + 2) * WSTRIDE + i] = w.z;
        wgtT[(e0 + 3) * WSTRIDE + i] = w.w;
    }
    // stage cat columns: center features then 3 rfeat blocks
    for (int idx = t; idx < 512; idx += 256) {
        int bb = idx >> 6, f = idx & 63;
        cat_b[bb * CSTRIDE + f] = features[(size_t)nodes[b0 + bb] * FEATD + f];
    }
#pragma unroll
    for (int r = 0; r < 3; ++r)
        for (int idx = t; idx < 512; idx += 256) {
            int bb = idx >> 6, j = idx & 63;
            cat_b[bb * CSTRIDE + 64 + r * 64 + j] =
                rfeat[((size_t)r * BN + b0 + bb) * EMB + j];
        }
    __syncthreads();

    int wv = t >> 6, lane = t & 63;     // lane = e
    int bb0 = wv * 2;
    float acc0 = 0.f, acc1 = 0.f;
    const float4* wrow = (const float4*)&wgtT[lane * WSTRIDE];
    const float4* c0p  = (const float4*)&cat_b[bb0 * CSTRIDE];
    const float4* c1p  = (const float4*)&cat_b[(bb0 + 1) * CSTRIDE];
#pragma unroll
    for (int i4 = 0; i4 < 64; ++i4) {
        float4 w = wrow[i4];
        float4 c0 = c0p[i4];             // wave-uniform broadcast
        float4 c1 = c1p[i4];
        acc0 += w.x*c0.x + w.y*c0.y + w.z*c0.z + w.w*c0.w;
        acc1 += w.x*c1.x + w.y*c1.y + w.z*c1.z + w.w*c1.w;
    }
    trans[bb0 * 65 + lane]       = fmaxf(acc0, 0.f);
    trans[(bb0 + 1) * 65 + lane] = fmaxf(acc1, 0.f);
    __syncthreads();

    // coalesced-ish store: out[e][b0..b0+8]
    for (int idx = t; idx < 512; idx += 256) {
        int e = idx >> 3, bb = idx & 7;
        out[(size_t)e * BN + b0 + bb] = trans[bb * 65 + e];
    }

    if (blockIdx.x == 0 && t == 0) {
        int k = smp[0];
        float s = 0.f;
        for (int i = 0; i < 24; ++i) s += ls[i];
        out[(size_t)EMB * BN] = s / (3.f * (float)BN * (float)k);
    }
}

// ----------------------------------------------------------------
extern "C" void kernel_launch(void* const* d_in, const int* in_sizes, int n_in,
                              void* d_out, int out_size, void* d_ws, size_t ws_size,
                              hipStream_t stream) {
    const int*   nodes     = (const int*)  d_in[0];
    // d_in[1] labels: unused
    const int*   neigh1    = (const int*)  d_in[2];
    const int*   neigh2    = (const int*)  d_in[3];
    const int*   neigh3    = (const int*)  d_in[4];
    const int*   pos_nodes = (const int*)  d_in[5];
    const float* features  = (const float*)d_in[6];
    const float* weight    = (const float*)d_in[7];
    const float* rsim      = (const float*)d_in[8];
    const float* pos_embs  = (const float*)d_in[9];
    const float* W1        = (const float*)d_in[10];
    const float* W2        = (const float*)d_in[11];
    const float* W3        = (const float*)d_in[12];
    const int*   smp       = (const int*)  d_in[13];
    float* out = (float*)d_out;
    float* ws  = (float*)d_ws;

    float4* node_sc = (float4*)(ws + WS_SC);
    float*  misc    = ws + WS_MISC;
    float*  lossacc = ws + WS_LOSS;
    float*  rfeat   = ws + WS_RF;

    node_precompute<<<dim3((NN + 255) / 256), dim3(256), 0, stream>>>(
        features, rsim, pos_embs, node_sc);
    pos_stats<<<dim3(1), dim3(1024), 0, stream>>>(
        pos_nodes, node_sc, pos_embs, misc, lossacc);
    relation_agg<<<dim3(BN / 4, 3), dim3(256), 0, stream>>>(
        neigh1, neigh2, neigh3, features, node_sc, W1, W2, W3,
        misc, lossacc, rfeat, smp);
    final_mm<<<dim3(BN / 8), dim3(256), 0, stream>>>(
        nodes, features, rfeat, weight, lossacc, smp, out);
}

// Round 4
// 83.408 us; speedup vs baseline: 3.3134x; 1.1557x over previous
//
#include <hip/hip_runtime.h>
#include <hip/hip_bf16.h>

#define NN     200000
#define FEATD  64
#define BN     4096
#define DEG    32
#define PP     2048
#define EMB    64
#define EPSV   1e-8f

// ws layout (float offsets)
#define WS_SC    0          // float4[NN]  {s0,s1,s2,norm}
#define WS_MISC  800000     // [0..2]=mean_pos  [4..6]=inv_pe
#define WS_LOSS  800064     // 24 slots, stride 32 floats (128B apart)
#define WS_RF    800832     // [3][BN][EMB]

// ---------------------------------------------------------------- kernel A
// Per node n: sim = relu(feat_n @ rsimTrans); store {dot(pe_r,sim)}_r, ||sim||.
// rsim/pos_embs are wave-uniform -> consumed via SGPR s_loads (no LDS at all).
// sim[64] lives in VGPRs; inner FMA is v_fma(vD, sS, vV).
__global__ __launch_bounds__(64) void node_precompute(
    const float* __restrict__ features, const float* __restrict__ rsim,
    const float* __restrict__ pos_embs, float4* __restrict__ node_sc)
{
    int n = blockIdx.x * 64 + threadIdx.x;   // grid*block == NN exactly

    const float4* fp = (const float4*)(features + (size_t)n * FEATD);
    float sim[64];
#pragma unroll
    for (int j = 0; j < 64; ++j) sim[j] = 0.f;

    for (int f4 = 0; f4 < 16; ++f4) {        // rolled: 16 iters
        float4 fv = fp[f4];
        const float* r0 = rsim + (f4 * 4 + 0) * 64;
        const float* r1 = rsim + (f4 * 4 + 1) * 64;
        const float* r2 = rsim + (f4 * 4 + 2) * 64;
        const float* r3 = rsim + (f4 * 4 + 3) * 64;
#pragma unroll
        for (int j = 0; j < 64; ++j) {       // scalar (SGPR) rs operands
            sim[j] += fv.x * r0[j];
            sim[j] += fv.y * r1[j];
            sim[j] += fv.z * r2[j];
            sim[j] += fv.w * r3[j];
        }
    }

    float s0 = 0.f, s1 = 0.f, s2 = 0.f, q = 0.f;
#pragma unroll
    for (int j = 0; j < 64; ++j) {
        float v = fmaxf(sim[j], 0.f);
        s0 += v * pos_embs[j];
        s1 += v * pos_embs[64 + j];
        s2 += v * pos_embs[128 + j];
        q  += v * v;
    }
    node_sc[n] = make_float4(s0, s1, s2, sqrtf(q));
}

// ---------------------------------------------------------------- kernel B
// pe inverse norms, mean(pos_scores) per relation, zero loss slots.
__global__ __launch_bounds__(1024) void pos_stats(
    const int* __restrict__ pos_nodes, const float4* __restrict__ node_sc,
    const float* __restrict__ pos_embs, float* __restrict__ misc,
    float* __restrict__ lossacc)
{
    __shared__ float invpe_s[3];
    __shared__ float wsum[16][3];
    int t = threadIdx.x, wv = t >> 6, lane = t & 63;

    if (t < 24) lossacc[t * 32] = 0.f;           // zero spread loss slots

    // pe norms: waves 0..2 each own one pos_emb row
    float pv = (t < 192) ? pos_embs[t] : 0.f;
    float q = pv * pv;
#pragma unroll
    for (int off = 32; off; off >>= 1) q += __shfl_down(q, off);
    if (t < 192 && lane == 0) {
        float inv = 1.f / fmaxf(sqrtf(q), EPSV);
        invpe_s[wv] = inv;
        misc[4 + wv] = inv;
    }
    __syncthreads();

    float i0 = invpe_s[0], i1 = invpe_s[1], i2 = invpe_s[2];
    float s0 = 0.f, s1 = 0.f, s2 = 0.f;
    for (int p = t; p < PP; p += 1024) {
        int n = pos_nodes[p];
        float4 sc = node_sc[n];
        float invn = 1.f / fmaxf(sc.w, EPSV);
        s0 += sc.x * i0 * invn;
        s1 += sc.y * i1 * invn;
        s2 += sc.z * i2 * invn;
    }
#pragma unroll
    for (int off = 32; off; off >>= 1) {
        s0 += __shfl_down(s0, off);
        s1 += __shfl_down(s1, off);
        s2 += __shfl_down(s2, off);
    }
    if (lane == 0) { wsum[wv][0] = s0; wsum[wv][1] = s1; wsum[wv][2] = s2; }
    __syncthreads();
    if (t < 3) {
        float s = 0.f;
        for (int w = 0; w < 16; ++w) s += wsum[w][t];
        misc[t] = s / (float)PP;
    }
}

// ---------------------------------------------------------------- kernel C
// One wave per (b, r): score 32 neighbors, stable top-k, parallel 16-row
// feature aggregate (4 independent dwordx4 loads), rfeat = relu(agg @ W_r).
__global__ __launch_bounds__(256) void relation_agg(
    const int* __restrict__ n1, const int* __restrict__ n2, const int* __restrict__ n3,
    const float* __restrict__ features, const float4* __restrict__ node_sc,
    const float* __restrict__ W1, const float* __restrict__ W2, const float* __restrict__ W3,
    const float* __restrict__ misc, float* __restrict__ lossacc,
    float* __restrict__ rfeat, const int* __restrict__ smp)
{
    int r = blockIdx.y;
    const int*   neigh = (r == 0) ? n1 : (r == 1) ? n2 : n3;
    const float* W     = (r == 0) ? W1 : (r == 1) ? W2 : W3;
    int k = smp[0];
    int t = threadIdx.x;
    int wv = t >> 6, lane = t & 63;
    int b = blockIdx.x * 4 + wv;
    float inv_pe   = misc[4 + r];
    float mean_pos = misc[r];

    __shared__ int sel_ids[4][32];

    // ---- score phase (lanes 0-31)
    float s = -1e30f;
    int   n = 0;
    if (lane < 32) {
        n = neigh[b * DEG + lane];
        float4 sc = node_sc[n];
        float num = (r == 0) ? sc.x : (r == 1) ? sc.y : sc.z;
        s = num * inv_pe / fmaxf(sc.w, EPSV);
    }
    // stable rank among 32 scores (ties -> lower index), matches lax.top_k
    int cnt = 0;
#pragma unroll
    for (int d2 = 0; d2 < 32; ++d2) {
        float v = __shfl(s, d2);
        cnt += ((v > s) || (v == s && d2 < lane)) ? 1 : 0;
    }
    bool sel = (lane < 32) && (cnt < k);
    if (sel) sel_ids[wv][cnt] = n;       // rank = unique slot in [0,k)

    float lv = sel ? (s - mean_pos) * (s - mean_pos) : 0.f;
#pragma unroll
    for (int off = 32; off; off >>= 1) lv += __shfl_down(lv, off);
    if (lane == 0)
        atomicAdd(&lossacc[(r * 8 + (blockIdx.x & 7)) * 32], lv);
    // no __syncthreads: sel_ids producer/consumer are the same wave (lgkmcnt)

    // ---- aggregate phase: 16 lanes per row, 4 rows per load wavefront
    const float4* F = (const float4*)features;
    int col   = lane & 15;           // float4 index within a 64-float row
    int rbase = lane >> 4;           // 0..3
    float4 a = make_float4(0.f, 0.f, 0.f, 0.f);
    if (k == 16) {
        int nid0 = sel_ids[wv][rbase];
        int nid1 = sel_ids[wv][rbase + 4];
        int nid2 = sel_ids[wv][rbase + 8];
        int nid3 = sel_ids[wv][rbase + 12];
        float4 v0 = F[(size_t)nid0 * 16 + col];
        float4 v1 = F[(size_t)nid1 * 16 + col];
        float4 v2 = F[(size_t)nid2 * 16 + col];
        float4 v3 = F[(size_t)nid3 * 16 + col];
        a.x = v0.x + v1.x + v2.x + v3.x;
        a.y = v0.y + v1.y + v2.y + v3.y;
        a.z = v0.z + v1.z + v2.z + v3.z;
        a.w = v0.w + v1.w + v2.w + v3.w;
    } else {
        for (int row0 = 0; row0 < k; row0 += 4) {
            int row = row0 + rbase;
            if (row < k) {
                int nid = sel_ids[wv][row];
                float4 v = F[(size_t)nid * 16 + col];
                a.x += v.x; a.y += v.y; a.z += v.z; a.w += v.w;
            }
        }
    }
    // allreduce across the 4 row-groups (xor 16, 32)
#pragma unroll
    for (int off = 16; off <= 32; off <<= 1) {
        a.x += __shfl_xor(a.x, off);
        a.y += __shfl_xor(a.y, off);
        a.z += __shfl_xor(a.z, off);
        a.w += __shfl_xor(a.w, off);
    }
    float inv_k = 1.f / (float)k;
    a.x *= inv_k; a.y *= inv_k; a.z *= inv_k; a.w *= inv_k;
    // lane l holds agg[cols (l&15)*4 .. +4], replicated across l>>4

    // ---- rfeat[e=lane] = relu(sum_j agg[j] * W[j][e])
    float acc = 0.f;
#pragma unroll
    for (int j4 = 0; j4 < 16; ++j4) {
        float a0 = __shfl(a.x, j4);
        float a1 = __shfl(a.y, j4);
        float a2 = __shfl(a.z, j4);
        float a3 = __shfl(a.w, j4);
        acc += a0 * W[(j4 * 4 + 0) * EMB + lane]
             + a1 * W[(j4 * 4 + 1) * EMB + lane]
             + a2 * W[(j4 * 4 + 2) * EMB + lane]
             + a3 * W[(j4 * 4 + 3) * EMB + lane];
    }
    rfeat[((size_t)r * BN + b) * EMB + lane] = fmaxf(acc, 0.f);
}

// ---------------------------------------------------------------- kernel D
// combined[e][b] = relu(cat[b] . weight[:,e]).
// 512 blocks, b-tile = 8. weight staged TRANSPOSED in LDS (stride 260 floats:
// 16B-aligned rows, superbank (65e+i/4)%8 -> conflict-free ds_read_b128).
// lane = e, wave owns 2 b-columns; cat columns broadcast from LDS.
#define WSTRIDE 260
#define CSTRIDE 264
__global__ __launch_bounds__(256) void final_mm(
    const int* __restrict__ nodes, const float* __restrict__ features,
    const float* __restrict__ rfeat, const float* __restrict__ weight,
    const float* __restrict__ lossacc, const int* __restrict__ smp,
    float* __restrict__ out)
{
    __shared__ float wgtT[64 * WSTRIDE];   // wgtT[e][i] = weight[i][e]
    __shared__ float cat_b[8 * CSTRIDE];   // cat_b[bb][i]
    __shared__ float trans[8 * 65];        // output transpose tile
    __shared__ float ls[24];
    int t = threadIdx.x;
    int b0 = blockIdx.x * 8;

    if (blockIdx.x == 0 && t < 24) ls[t] = lossacc[t * 32];

    // stage weight transposed: 4096 float4 / 256 threads = 16 iters
    const float4* wp4 = (const float4*)weight;
    for (int idx = t; idx < 4096; idx += 256) {
        int i = idx >> 4, e0 = (idx & 15) << 2;
        float4 w = wp4[idx];
        wgtT[(e0 + 0) * WSTRIDE + i] = w.x;
        wgtT[(e0 + 1) * WSTRIDE + i] = w.y;
        wgtT[(e0 + 2) * WSTRIDE + i] = w.z;
        wgtT[(e0 + 3) * WSTRIDE + i] = w.w;
    }
    // stage cat columns: center features then 3 rfeat blocks
    for (int idx = t; idx < 512; idx += 256) {
        int bb = idx >> 6, f = idx & 63;
        cat_b[bb * CSTRIDE + f] = features[(size_t)nodes[b0 + bb] * FEATD + f];
    }
#pragma unroll
    for (int r = 0; r < 3; ++r)
        for (int idx = t; idx < 512; idx += 256) {
            int bb = idx >> 6, j = idx & 63;
            cat_b[bb * CSTRIDE + 64 + r * 64 + j] =
                rfeat[((size_t)r * BN + b0 + bb) * EMB + j];
        }
    __syncthreads();

    int wv = t >> 6, lane = t & 63;     // lane = e
    int bb0 = wv * 2;
    float acc0 = 0.f, acc1 = 0.f;
    const float4* wrow = (const float4*)&wgtT[lane * WSTRIDE];
    const float4* c0p  = (const float4*)&cat_b[bb0 * CSTRIDE];
    const float4* c1p  = (const float4*)&cat_b[(bb0 + 1) * CSTRIDE];
#pragma unroll
    for (int i4 = 0; i4 < 64; ++i4) {
        float4 w = wrow[i4];
        float4 c0 = c0p[i4];             // wave-uniform broadcast
        float4 c1 = c1p[i4];
        acc0 += w.x*c0.x + w.y*c0.y + w.z*c0.z + w.w*c0.w;
        acc1 += w.x*c1.x + w.y*c1.y + w.z*c1.z + w.w*c1.w;
    }
    trans[bb0 * 65 + lane]       = fmaxf(acc0, 0.f);
    trans[(bb0 + 1) * 65 + lane] = fmaxf(acc1, 0.f);
    __syncthreads();

    // coalesced-ish store: out[e][b0..b0+8]
    for (int idx = t; idx < 512; idx += 256) {
        int e = idx >> 3, bb = idx & 7;
        out[(size_t)e * BN + b0 + bb] = trans[bb * 65 + e];
    }

    if (blockIdx.x == 0 && t == 0) {
        int k = smp[0];
        float s = 0.f;
        for (int i = 0; i < 24; ++i) s += ls[i];
        out[(size_t)EMB * BN] = s / (3.f * (float)BN * (float)k);
    }
}

// ----------------------------------------------------------------
extern "C" void kernel_launch(void* const* d_in, const int* in_sizes, int n_in,
                              void* d_out, int out_size, void* d_ws, size_t ws_size,
                              hipStream_t stream) {
    const int*   nodes     = (const int*)  d_in[0];
    // d_in[1] labels: unused
    const int*   neigh1    = (const int*)  d_in[2];
    const int*   neigh2    = (const int*)  d_in[3];
    const int*   neigh3    = (const int*)  d_in[4];
    const int*   pos_nodes = (const int*)  d_in[5];
    const float* features  = (const float*)d_in[6];
    const float* weight    = (const float*)d_in[7];
    const float* rsim      = (const float*)d_in[8];
    const float* pos_embs  = (const float*)d_in[9];
    const float* W1        = (const float*)d_in[10];
    const float* W2        = (const float*)d_in[11];
    const float* W3        = (const float*)d_in[12];
    const int*   smp       = (const int*)  d_in[13];
    float* out = (float*)d_out;
    float* ws  = (float*)d_ws;

    float4* node_sc = (float4*)(ws + WS_SC);
    float*  misc    = ws + WS_MISC;
    float*  lossacc = ws + WS_LOSS;
    float*  rfeat   = ws + WS_RF;

    node_precompute<<<dim3(NN / 64), dim3(64), 0, stream>>>(
        features, rsim, pos_embs, node_sc);
    pos_stats<<<dim3(1), dim3(1024), 0, stream>>>(
        pos_nodes, node_sc, pos_embs, misc, lossacc);
    relation_agg<<<dim3(BN / 4, 3), dim3(256), 0, stream>>>(
        neigh1, neigh2, neigh3, features, node_sc, W1, W2, W3,
        misc, lossacc, rfeat, smp);
    final_mm<<<dim3(BN / 8), dim3(256), 0, stream>>>(
        nodes, features, rfeat, weight, lossacc, smp, out);
}